// Round 22
// baseline (121.893 us; speedup 1.0000x reference)
//
#include <hip/hip_runtime.h>
#include <math.h>

#define BB 131072
#define HH 64
#define NOB 32
#define NDIRS 8
#define LR_IT 1e-3f
#define TOLV 1e-3f
#define EPSV 1e-6f
#define NBLK 512
#define NBF  2048      // fused grid (64 rows/block)
#define RPB  64
#define TPB 256
#define WRS 68
#define WOS 36
#define INV_BH (1.0f/8388608.0f)

typedef _Float16 f16x8 __attribute__((ext_vector_type(8)));
typedef float f32x4v __attribute__((ext_vector_type(4)));

// ---------------- legacy helpers (resolve/step/final, proven r11 bodies) --------------
#define D16(pp, Wp, b) ((pp).x*(Wp)[(b)+0] + (pp).y*(Wp)[(b)+1] + (pp).z*(Wp)[(b)+2] + (pp).w*(Wp)[(b)+3])
#define DOT64P(Wp) (D16(p0,Wp,0)+D16(p1,Wp,4)+D16(p2,Wp,8)+D16(p3,Wp,12)+ \
                    D16(p4,Wp,16)+D16(p5,Wp,20)+D16(p6,Wp,24)+D16(p7,Wp,28)+ \
                    D16(p8,Wp,32)+D16(p9,Wp,36)+D16(p10,Wp,40)+D16(p11,Wp,44)+ \
                    D16(p12,Wp,48)+D16(p13,Wp,52)+D16(p14,Wp,56)+D16(p15,Wp,60))
#define LOADP(src) \
  float4 p0=(src)[0], p1=(src)[1], p2=(src)[2], p3=(src)[3], \
         p4=(src)[4], p5=(src)[5], p6=(src)[6], p7=(src)[7], \
         p8=(src)[8], p9=(src)[9], p10=(src)[10], p11=(src)[11], \
         p12=(src)[12], p13=(src)[13], p14=(src)[14], p15=(src)[15];
#define SUMSQ4(pp) ((pp).x*(pp).x + (pp).y*(pp).y + (pp).z*(pp).z + (pp).w*(pp).w)
#define SUM4(pp) ((pp).x + (pp).y + (pp).z + (pp).w)

__device__ __forceinline__ void stage_wr(const float* __restrict__ Wr, float* wrl, int t, int bs) {
  const float4* g = (const float4*)Wr;
  for (int i = t; i < 1024; i += bs) {
    int h = i >> 4, k4 = i & 15;
    *(float4*)&wrl[h * WRS + k4 * 4] = g[i];
  }
}
__device__ __forceinline__ void stage_wot(const float* __restrict__ Wout, float* wot, int t, int bs) {
  for (int i = t; i < NOB * HH; i += bs) {
    int o = i >> 6, h = i & 63;
    wot[h * WOS + o] = Wout[i];
  }
}
__device__ __forceinline__ void stage_wint(const float* __restrict__ Win, float* wint, int t, int bs) {
  for (int i = t; i < HH * NDIRS; i += bs) {
    int h = i >> 3, d = i & 7;
    wint[d * WRS + h] = Win[i];
  }
}

__device__ __forceinline__ float block_reduce_all(float v, float* red, int t) {
  #pragma unroll
  for (int off = 32; off > 0; off >>= 1) v += __shfl_down(v, off);
  __syncthreads();
  if ((t & 63) == 0) red[t >> 6] = v;
  __syncthreads();
  return red[0] + red[1] + red[2] + red[3];
}

// reduce the NBF-entry gate array with a 256-thread block
__device__ __forceinline__ float gate_reduce_nbf(const float* __restrict__ p, float* red, int t) {
  float v = 0.f;
  #pragma unroll
  for (int j = 0; j < NBF / TPB; ++j) v += p[t + TPB * j];
  return block_reduce_all(v, red, t);
}

#define SOFTJP(zzp, a_sv, obv) { \
  float m_ = -1e30f; \
  _Pragma("unroll") for (int o_=0;o_<NOB;++o_) m_ = fmaxf(m_, (zzp)[o_]); \
  float se_ = 0.f; \
  _Pragma("unroll") for (int o_=0;o_<NOB;++o_){ (zzp)[o_]=__expf((a_sv)*((zzp)[o_]-m_)); se_+=(zzp)[o_];} \
  float rse_ = 1.f/se_; float fob_=0.f, sf2_=0.f; \
  _Pragma("unroll") for (int o_=0;o_<NOB;++o_){ float f_=(zzp)[o_]*rse_; (zzp)[o_]=f_; sf2_+=f_*f_; fob_ += (o_==(obv))?f_:0.f;} \
  float fe_ = fob_ - sf2_; \
  _Pragma("unroll") for (int o_=0;o_<NOB;++o_){ float ep_=((o_==(obv))?1.f:0.f)-(zzp)[o_]; (zzp)[o_]=(zzp)[o_]*(ep_-fe_);} }

__device__ __forceinline__ void final_write(
    int r, float a_s, const float* __restrict__ S, float* __restrict__ out,
    const float* wot) {
  const float4* __restrict__ sr4 = (const float4*)(S + (size_t)r * HH);
  float zz[NOB];
  #pragma unroll
  for (int o = 0; o < NOB; ++o) zz[o] = 0.f;
  #pragma unroll 1
  for (int h0 = 0; h0 < 16; ++h0) {
    float4 s4 = sr4[h0];
    const float* t0 = &wot[(h0 * 4 + 0) * WOS];
    const float* t1 = &wot[(h0 * 4 + 1) * WOS];
    const float* t2 = &wot[(h0 * 4 + 2) * WOS];
    const float* t3 = &wot[(h0 * 4 + 3) * WOS];
    #pragma unroll
    for (int o = 0; o < NOB; ++o)
      zz[o] += s4.x * t0[o] + s4.y * t1[o] + s4.z * t2[o] + s4.w * t3[o];
  }
  float m = -1e30f;
  #pragma unroll
  for (int o = 0; o < NOB; ++o) m = fmaxf(m, zz[o]);
  float se = 0.f;
  #pragma unroll
  for (int o = 0; o < NOB; ++o) { zz[o] = __expf(a_s * (zz[o] - m)); se += zz[o]; }
  float rse = 1.f / se;

  float4* po = (float4*)(out + (size_t)r * NOB);
  #pragma unroll
  for (int o4 = 0; o4 < 8; ++o4) {
    float4 f;
    f.x = zz[o4 * 4 + 0] * rse; f.y = zz[o4 * 4 + 1] * rse;
    f.z = zz[o4 * 4 + 2] * rse; f.w = zz[o4 * 4 + 3] * rse;
    po[o4] = f;
  }
  float4* so = (float4*)(out + (size_t)BB * NOB + (size_t)r * HH);
  #pragma unroll 1
  for (int h0 = 0; h0 < 16; ++h0) {
    float4 s4 = sr4[h0];
    s4.x *= a_s; s4.y *= a_s; s4.z *= a_s; s4.w *= a_s;
    so[h0] = s4;
  }
}

// ---- helper: load 8 consecutive f32 -> f16x8 fragment ----
__device__ __forceinline__ f16x8 ldb8(const float* __restrict__ p) {
  float4 a = *(const float4*)p;
  float4 b = *(const float4*)(p + 4);
  f16x8 r;
  r[0]=(_Float16)a.x; r[1]=(_Float16)a.y; r[2]=(_Float16)a.z; r[3]=(_Float16)a.w;
  r[4]=(_Float16)b.x; r[5]=(_Float16)b.y; r[6]=(_Float16)b.z; r[7]=(_Float16)b.w;
  return r;
}
// load 8 f32 at stride (in floats) from LDS -> f16x8 fragment (column gather)
__device__ __forceinline__ f16x8 ldb8s(const float* p, int stride) {
  f16x8 r;
  #pragma unroll
  for (int i = 0; i < 8; ++i) r[i] = (_Float16)p[i * stride];
  return r;
}

#define MFMA16(a, b, c) __builtin_amdgcn_mfma_f32_16x16x32_f16((a), (b), (c), 0, 0, 0)

// ---- fused (MFMA): init + iteration-0 candidate + SPECULATIVE final output ----
// 1 wave = 16 rows, 4 waves/block; waves-per-EU hint 5 (VGPR cap ~102 > 64 used).
__global__ __launch_bounds__(TPB, 5) void fused_kernel(
    const float* __restrict__ x, const int* __restrict__ dirs,
    const int* __restrict__ obs,
    const float* __restrict__ Wr, const float* __restrict__ Wout,
    const float* __restrict__ Win,
    float* __restrict__ buf0, float* __restrict__ buf1,
    float* __restrict__ scl0, float* __restrict__ scl1,
    float* __restrict__ partials0, float* __restrict__ partials1,
    float* __restrict__ out)
{
  __shared__ float s0sh[4 * 16 * 68];
  __shared__ float jpsh[4 * 16 * 36];
  __shared__ float red0[4], red1[4];
  int t = threadIdx.x;
  int w = t >> 6, l = t & 63;
  int l15 = l & 15, lg = l >> 4;
  int rbase = blockIdx.x * RPB + w * 16;
  float* s0l = &s0sh[w * 16 * 68];
  float* jpl = &jpsh[w * 16 * 36];

  // ---- stage Wout into s0sh (padded stride 66 -> bank-spread column gathers) ----
  for (int i = t; i < NOB * HH; i += TPB) {
    int o = i >> 6, h = i & 63;
    s0sh[o * 66 + h] = Wout[i];
  }

  // ---- contiguous global B-fragments (overlap the staging latency) ----
  f16x8 bWr[4][2];
  #pragma unroll
  for (int T = 0; T < 4; ++T)
    #pragma unroll
    for (int c = 0; c < 2; ++c)
      bWr[T][c] = ldb8(Wr + (size_t)(16*T + l15) * HH + 32*c + lg*8);
  f16x8 bWo[2][2];
  #pragma unroll
  for (int T = 0; T < 2; ++T)
    #pragma unroll
    for (int c = 0; c < 2; ++c)
      bWo[T][c] = ldb8(Wout + (size_t)(16*T + l15) * HH + 32*c + lg*8);

  __syncthreads();   // staged Wout visible
  // GEMM3 B[k=o][j=h]: element i -> Wout[(lg*8+i)][16T+l15] from LDS (stride 66)
  f16x8 bWt[4];
  #pragma unroll
  for (int T = 0; T < 4; ++T)
    bWt[T] = ldb8s(s0sh + (lg*8) * 66 + 16*T + l15, 66);
  __syncthreads();   // s0sh released for reuse as the s0 tile

  // ---- phase 1: x A-frags + row stats ----
  const float4* __restrict__ xr = (const float4*)(x + (size_t)(rbase + l15) * HH);
  float4 xa0 = xr[lg*2],     xa1 = xr[lg*2 + 1];
  float4 xb0 = xr[8 + lg*2], xb1 = xr[8 + lg*2 + 1];
  f16x8 ax0, ax1;
  {
    f16x8 r;
    r[0]=(_Float16)xa0.x; r[1]=(_Float16)xa0.y; r[2]=(_Float16)xa0.z; r[3]=(_Float16)xa0.w;
    r[4]=(_Float16)xa1.x; r[5]=(_Float16)xa1.y; r[6]=(_Float16)xa1.z; r[7]=(_Float16)xa1.w;
    ax0 = r;
    r[0]=(_Float16)xb0.x; r[1]=(_Float16)xb0.y; r[2]=(_Float16)xb0.z; r[3]=(_Float16)xb0.w;
    r[4]=(_Float16)xb1.x; r[5]=(_Float16)xb1.y; r[6]=(_Float16)xb1.z; r[7]=(_Float16)xb1.w;
    ax1 = r;
  }
  float ssx = SUMSQ4(xa0)+SUMSQ4(xa1)+SUMSQ4(xb0)+SUMSQ4(xb1);
  float sx  = SUM4(xa0)+SUM4(xa1)+SUM4(xb0)+SUM4(xb1);
  ssx += __shfl_xor(ssx, 16); ssx += __shfl_xor(ssx, 32);
  sx  += __shfl_xor(sx, 16);  sx  += __shfl_xor(sx, 32);
  float inv_x = 1.f / (sqrtf(ssx) + EPSV);   // row l15

  // ---- GEMM1 ----
  f32x4v acc[4];
  #pragma unroll
  for (int T = 0; T < 4; ++T) {
    f32x4v c = {0.f, 0.f, 0.f, 0.f};
    c = MFMA16(ax0, bWr[T][0], c);
    c = MFMA16(ax1, bWr[T][1], c);
    acc[T] = c;
  }

  // ---- phase 3: s0 = relu(inv_x*acc + drive) ----
  float invxr[4], sxr[4];
  int dirr[4], obr[4];
  #pragma unroll
  for (int reg = 0; reg < 4; ++reg) {
    invxr[reg] = __shfl(inv_x, 4*lg + reg);
    sxr[reg]   = __shfl(sx,    4*lg + reg);
    dirr[reg]  = dirs[rbase + 4*lg + reg];
    obr[reg]   = obs [rbase + 4*lg + reg];
  }
  float s0v[4][4];    // [T][reg]
  float ssg[4] = {0.f,0.f,0.f,0.f}, sgv[4] = {0.f,0.f,0.f,0.f};
  #pragma unroll
  for (int T = 0; T < 4; ++T)
    #pragma unroll
    for (int reg = 0; reg < 4; ++reg) {
      float drive = Win[(size_t)(16*T + l15) * NDIRS + dirr[reg]];
      float v = fmaxf(fmaf(invxr[reg], acc[T][reg], drive), 0.f);
      s0v[T][reg] = v;
      ssg[reg] += v * v; sgv[reg] += v;
    }
  #pragma unroll
  for (int reg = 0; reg < 4; ++reg) {
    #pragma unroll
    for (int m = 1; m < 16; m <<= 1) {
      ssg[reg] += __shfl_xor(ssg[reg], m);
      sgv[reg] += __shfl_xor(sgv[reg], m);
    }
  }
  float invg[4];
  #pragma unroll
  for (int reg = 0; reg < 4; ++reg) invg[reg] = 1.f / (sqrtf(ssg[reg]) + EPSV);
  if (l15 == 0) {
    #pragma unroll
    for (int reg = 0; reg < 4; ++reg) scl0[rbase + 4*lg + reg] = invg[reg];
  }
  float g0 = 0.f;
  if (l15 == 0) {
    #pragma unroll
    for (int reg = 0; reg < 4; ++reg)
      g0 += invxr[reg] * sxr[reg] - invg[reg] * sgv[reg];
  }

  // s0 -> LDS tile ; coalesced buf0 write
  #pragma unroll
  for (int T = 0; T < 4; ++T)
    #pragma unroll
    for (int reg = 0; reg < 4; ++reg)
      s0l[(4*lg + reg) * 68 + 16*T + l15] = s0v[T][reg];
  {
    int rr = l >> 2, cc = (l & 3) * 16;
    const float4* srcl = (const float4*)(s0l + rr * 68 + cc);
    float4* dst = (float4*)(buf0 + (size_t)(rbase + rr) * HH + cc);
    dst[0] = srcl[0]; dst[1] = srcl[1]; dst[2] = srcl[2]; dst[3] = srcl[3];
  }

  // ---- GEMM2: logits = s0 @ WoutT ----
  f16x8 as0, as1;
  {
    const float* pr = s0l + l15 * 68 + lg * 8;
    as0 = ldb8(pr);
    as1 = ldb8(pr + 32);
  }
  f32x4v lac[2];
  #pragma unroll
  for (int T = 0; T < 2; ++T) {
    f32x4v c = {0.f, 0.f, 0.f, 0.f};
    c = MFMA16(as0, bWo[T][0], c);
    c = MFMA16(as1, bWo[T][1], c);
    lac[T] = c;
  }

  // ---- phase 5: softmax + jacobian per row ----
  float jp0[4], jp1[4];
  #pragma unroll
  for (int reg = 0; reg < 4; ++reg) {
    float z0 = lac[0][reg], z1 = lac[1][reg];
    float m = fmaxf(z0, z1);
    #pragma unroll
    for (int mm = 1; mm < 16; mm <<= 1) m = fmaxf(m, __shfl_xor(m, mm));
    float e0 = __expf(invg[reg] * (z0 - m));
    float e1 = __expf(invg[reg] * (z1 - m));
    float se = e0 + e1;
    #pragma unroll
    for (int mm = 1; mm < 16; mm <<= 1) se += __shfl_xor(se, mm);
    float rse = 1.f / se;
    float f0 = e0 * rse, f1 = e1 * rse;
    int ob = obr[reg];
    float on0 = (l15 == ob) ? 1.f : 0.f;
    float on1 = (16 + l15 == ob) ? 1.f : 0.f;
    float fob = on0 * f0 + on1 * f1;
    float sf2 = f0 * f0 + f1 * f1;
    #pragma unroll
    for (int mm = 1; mm < 16; mm <<= 1) {
      fob += __shfl_xor(fob, mm);
      sf2 += __shfl_xor(sf2, mm);
    }
    float fe = fob - sf2;
    jp0[reg] = f0 * (on0 - f0 - fe);
    jp1[reg] = f1 * (on1 - f1 - fe);
  }

  #pragma unroll
  for (int reg = 0; reg < 4; ++reg) {
    jpl[(4*lg + reg) * 36 + l15]      = jp0[reg];
    jpl[(4*lg + reg) * 36 + 16 + l15] = jp1[reg];
  }
  f16x8 ajp;
  {
    const float* pr = jpl + l15 * 36 + lg * 8;
    ajp = ldb8(pr);
  }

  // ---- GEMM3: pv = jp @ Wout ----
  f32x4v pv[4];
  #pragma unroll
  for (int T = 0; T < 4; ++T) {
    f32x4v c = {0.f, 0.f, 0.f, 0.f};
    pv[T] = MFMA16(ajp, bWt[T], c);
  }

  // ---- phase 8: s1 = sv + LR*(s0 - sv + pv); normalize IN PLACE; gates ----
  float ssu[4] = {0.f,0.f,0.f,0.f}, suv[4] = {0.f,0.f,0.f,0.f};
  #pragma unroll
  for (int T = 0; T < 4; ++T)
    #pragma unroll
    for (int reg = 0; reg < 4; ++reg) {
      float s0_ = s0v[T][reg];
      float sv = invg[reg] * s0_;
      float u = fmaf(LR_IT, s0_ - sv + pv[T][reg], sv);
      s0v[T][reg] = u;            // raw s1
      ssu[reg] += u * u; suv[reg] += u;
    }
  #pragma unroll
  for (int reg = 0; reg < 4; ++reg) {
    #pragma unroll
    for (int m = 1; m < 16; m <<= 1) {
      ssu[reg] += __shfl_xor(ssu[reg], m);
      suv[reg] += __shfl_xor(suv[reg], m);
    }
  }
  float invu[4];
  #pragma unroll
  for (int reg = 0; reg < 4; ++reg) invu[reg] = 1.f / (sqrtf(ssu[reg]) + EPSV);
  // buf1 holds NORMALIZED s1 -> effective downstream scale is 1.0
  if (l15 == 0) {
    #pragma unroll
    for (int reg = 0; reg < 4; ++reg) scl1[rbase + 4*lg + reg] = 1.0f;
  }
  float g1 = 0.f;
  if (l15 == 0) {
    #pragma unroll
    for (int reg = 0; reg < 4; ++reg)
      g1 += invg[reg] * sgv[reg] - invu[reg] * suv[reg];
  }
  #pragma unroll
  for (int T = 0; T < 4; ++T)
    #pragma unroll
    for (int reg = 0; reg < 4; ++reg)
      s0v[T][reg] *= invu[reg];   // normalized s1

  // normalized s1 -> LDS tile -> coalesced buf1 (= out s-slice) write
  #pragma unroll
  for (int T = 0; T < 4; ++T)
    #pragma unroll
    for (int reg = 0; reg < 4; ++reg)
      s0l[(4*lg + reg) * 68 + 16*T + l15] = s0v[T][reg];
  {
    int rr = l >> 2, cc = (l & 3) * 16;
    const float4* srcl = (const float4*)(s0l + rr * 68 + cc);
    float4* dst = (float4*)(buf1 + (size_t)(rbase + rr) * HH + cc);
    dst[0] = srcl[0]; dst[1] = srcl[1]; dst[2] = srcl[2]; dst[3] = srcl[3];
  }

  // ---- speculative final: preds = softmax(s1n @ WoutT) -> out[:B*32] ----
  {
    const float* pr = s0l + l15 * 68 + lg * 8;
    f16x8 a0 = ldb8(pr);
    f16x8 a1 = ldb8(pr + 32);
    f32x4v pl0 = {0.f,0.f,0.f,0.f}, pl1 = {0.f,0.f,0.f,0.f};
    pl0 = MFMA16(a0, bWo[0][0], pl0); pl0 = MFMA16(a1, bWo[0][1], pl0);
    pl1 = MFMA16(a0, bWo[1][0], pl1); pl1 = MFMA16(a1, bWo[1][1], pl1);
    #pragma unroll
    for (int reg = 0; reg < 4; ++reg) {
      float z0 = pl0[reg], z1 = pl1[reg];
      float m = fmaxf(z0, z1);
      #pragma unroll
      for (int mm = 1; mm < 16; mm <<= 1) m = fmaxf(m, __shfl_xor(m, mm));
      float e0 = __expf(z0 - m), e1 = __expf(z1 - m);
      float se = e0 + e1;
      #pragma unroll
      for (int mm = 1; mm < 16; mm <<= 1) se += __shfl_xor(se, mm);
      float rse = 1.f / se;
      jpl[(4*lg + reg) * 36 + l15]      = e0 * rse;
      jpl[(4*lg + reg) * 36 + 16 + l15] = e1 * rse;
    }
    int rr = l >> 2, cc = (l & 3) * 8;
    const float4* srcl = (const float4*)(jpl + rr * 36 + cc);
    float4* dst = (float4*)(out + (size_t)(rbase + rr) * NOB + cc);
    dst[0] = srcl[0]; dst[1] = srcl[1];
  }

  // ---- gates: wave totals -> block totals ----
  g0 += __shfl_xor(g0, 16); g0 += __shfl_xor(g0, 32);
  g1 += __shfl_xor(g1, 16); g1 += __shfl_xor(g1, 32);
  if (l == 0) { red0[w] = g0; red1[w] = g1; }
  __syncthreads();
  if (t == 0) {
    partials0[blockIdx.x] = red0[0] + red0[1] + red0[2] + red0[3];
    partials1[blockIdx.x] = red1[0] + red1[1] + red1[2] + red1[3];
  }
}

// ---- resolve: decide act0/act1; expected path is a no-op (fused wrote output) ----
__global__ __launch_bounds__(TPB, 2) void resolve_kernel(
    float* __restrict__ buf0, float* __restrict__ buf1,
    float* __restrict__ scl0, float* __restrict__ scl1,
    const float* __restrict__ Wr, const float* __restrict__ Wout,
    const float* __restrict__ Win,
    const int* __restrict__ dirs, const int* __restrict__ obs,
    const float* __restrict__ partials0, float* __restrict__ partials,
    int* __restrict__ actArr, float* __restrict__ out)
{
  __shared__ float wrl[HH * WRS];
  __shared__ float wot[HH * WOS];
  __shared__ float wint[NDIRS * WRS];
  __shared__ float red[4];
  int t = threadIdx.x;

  float t0v = gate_reduce_nbf(partials0, red, t);
  int act0 = (fabsf(t0v * INV_BH) > TOLV) ? 1 : 0;
  float t1v = gate_reduce_nbf(partials, red, t);
  int act1 = (fabsf(t1v * INV_BH) > TOLV) ? 1 : 0;
  if (blockIdx.x == 0 && t == 0) actArr[1] = act0 && act1;

  int r = blockIdx.x * TPB + t;

  if (!act0) {
    // iteration 0 inactive: final = s0 (overwrite speculative s1 output)
    if (t < 4) partials[blockIdx.x * 4 + t] = partials0[blockIdx.x * 4 + t];
    stage_wot(Wout, wot, t, TPB);
    __syncthreads();
    final_write(r, scl0[r], buf0, out, wot);
    return;
  }
  if (!act1) return;   // EXPECTED PATH: fused already wrote preds + normalized s1

  // both active: run iteration 1 fully. S=buf1 (normalized, scl1==1), P=buf0, W=buf0/scl0.
  stage_wr(Wr, wrl, t, TPB);
  stage_wot(Wout, wot, t, TPB);
  stage_wint(Win, wint, t, TPB);
  __syncthreads();

  float a_s = scl1[r];
  float a_p = scl0[r];
  int ob = obs[r];
  int dir = dirs[r];
  const float4* __restrict__ sr4 = (const float4*)(buf1 + (size_t)r * HH);

  float zz[NOB];
  #pragma unroll
  for (int o = 0; o < NOB; ++o) zz[o] = 0.f;
  float sS = 0.f;
  #pragma unroll 1
  for (int h0 = 0; h0 < 16; ++h0) {
    float4 s4 = sr4[h0];
    sS += SUM4(s4);
    const float* t0 = &wot[(h0 * 4 + 0) * WOS];
    const float* t1 = &wot[(h0 * 4 + 1) * WOS];
    const float* t2 = &wot[(h0 * 4 + 2) * WOS];
    const float* t3 = &wot[(h0 * 4 + 3) * WOS];
    #pragma unroll
    for (int o = 0; o < NOB; ++o)
      zz[o] += s4.x * t0[o] + s4.y * t1[o] + s4.z * t2[o] + s4.w * t3[o];
  }
  SOFTJP(zz, a_s, ob)
  __syncthreads();   // live-range firewall

  const float4* __restrict__ pr4 = (const float4*)(buf0 + (size_t)r * HH);
  LOADP(pr4);
  float4* wo4 = (float4*)(buf0 + (size_t)r * HH);
  float ssu = 0.f, su = 0.f;
#define STEP_C_ONE(JJ, COMP) { \
    const float* wr_ = &wrl[(h0 * 4 + JJ) * WRS]; \
    float g_ = fmaxf(fmaf(a_p, DOT64P(wr_), d4.COMP), 0.f); \
    const float* wt_ = &wot[(h0 * 4 + JJ) * WOS]; \
    float w_ = 0.f; \
    _Pragma("unroll") \
    for (int o = 0; o < NOB; ++o) w_ += zz[o] * wt_[o]; \
    float sv_ = a_s * s4.COMP; \
    float uu_ = fmaf(LR_IT, g_ - sv_ + w_, sv_); \
    u.COMP = uu_; ssu += uu_ * uu_; su += uu_; }
  #pragma unroll 1
  for (int h0 = 0; h0 < 16; ++h0) {
    float4 s4 = sr4[h0];
    float4 d4 = *(const float4*)&wint[dir * WRS + h0 * 4];
    float4 u;
    STEP_C_ONE(0, x) STEP_C_ONE(1, y) STEP_C_ONE(2, z) STEP_C_ONE(3, w)
    wo4[h0] = u;
  }
  float inv_u = 1.f / (sqrtf(ssu) + EPSV);
  scl0[r] = inv_u;

  float tot2 = block_reduce_all(a_s * sS - inv_u * su, red, t);
  if (t == 0) partials[blockIdx.x] = tot2;
  if (t == 1) partials[blockIdx.x + NBLK] = 0.f;
  if (t == 2) partials[blockIdx.x + 2 * NBLK] = 0.f;
  if (t == 3) partials[blockIdx.x + 3 * NBLK] = 0.f;
}

// ---- generic step k>=2: gate + (active | first-inactive final | no-op) ----
__global__ __launch_bounds__(TPB, 2) void step_kernel(
    float* __restrict__ buf0, float* __restrict__ buf1,
    float* __restrict__ scl0, float* __restrict__ scl1,
    const float* __restrict__ Wr, const float* __restrict__ Wout,
    const float* __restrict__ Win,
    const int* __restrict__ dirs, const int* __restrict__ obs,
    float* __restrict__ partials, int* __restrict__ actArr,
    float* __restrict__ out, int k)
{
  __shared__ float red[4];
  __shared__ float wrl[HH * WRS];
  __shared__ float wot[HH * WOS];
  __shared__ float wint[NDIRS * WRS];
  int t = threadIdx.x;

  float tot = gate_reduce_nbf(partials, red, t);
  int active = (fabsf(tot * INV_BH) > TOLV) ? 1 : 0;
  if (blockIdx.x == 0 && t == 0) actArr[k] = active;

  int si = k & 1;
  int r = blockIdx.x * TPB + t;

  if (!active) {
    int first_inactive = actArr[k - 1];
    if (!first_inactive) return;
    stage_wot(Wout, wot, t, TPB);
    __syncthreads();
    const float* S   = si ? buf1 : buf0;
    const float* scl = si ? scl1 : scl0;
    final_write(r, scl[r], S, out, wot);
    return;
  }

  const float* S    = si ? buf1 : buf0;
  const float* sclS = si ? scl1 : scl0;
  float* W          = si ? buf0 : buf1;
  float* sclW       = si ? scl0 : scl1;

  stage_wr(Wr, wrl, t, TPB);
  stage_wot(Wout, wot, t, TPB);
  stage_wint(Win, wint, t, TPB);
  __syncthreads();

  float a_s = sclS[r];
  float a_p = sclW[r];
  int ob = obs[r];
  int dir = dirs[r];
  const float4* __restrict__ sr4 = (const float4*)(S + (size_t)r * HH);

  float zz[NOB];
  #pragma unroll
  for (int o = 0; o < NOB; ++o) zz[o] = 0.f;
  float sS = 0.f;
  #pragma unroll 1
  for (int h0 = 0; h0 < 16; ++h0) {
    float4 s4 = sr4[h0];
    sS += SUM4(s4);
    const float* t0 = &wot[(h0 * 4 + 0) * WOS];
    const float* t1 = &wot[(h0 * 4 + 1) * WOS];
    const float* t2 = &wot[(h0 * 4 + 2) * WOS];
    const float* t3 = &wot[(h0 * 4 + 3) * WOS];
    #pragma unroll
    for (int o = 0; o < NOB; ++o)
      zz[o] += s4.x * t0[o] + s4.y * t1[o] + s4.z * t2[o] + s4.w * t3[o];
  }
  SOFTJP(zz, a_s, ob)
  __syncthreads();

  const float4* __restrict__ pr4 = (const float4*)(W + (size_t)r * HH);
  LOADP(pr4);
  float4* wo4 = (float4*)(W + (size_t)r * HH);
  float ssu = 0.f, su = 0.f;
  #pragma unroll 1
  for (int h0 = 0; h0 < 16; ++h0) {
    float4 s4 = sr4[h0];
    float4 d4 = *(const float4*)&wint[dir * WRS + h0 * 4];
    float4 u;
    STEP_C_ONE(0, x) STEP_C_ONE(1, y) STEP_C_ONE(2, z) STEP_C_ONE(3, w)
    wo4[h0] = u;
  }
  float inv_u = 1.f / (sqrtf(ssu) + EPSV);
  sclW[r] = inv_u;

  float tot2 = block_reduce_all(a_s * sS - inv_u * su, red, t);
  if (t == 0) partials[blockIdx.x] = tot2;
  if (t == 1) partials[blockIdx.x + NBLK] = 0.f;
  if (t == 2) partials[blockIdx.x + 2 * NBLK] = 0.f;
  if (t == 3) partials[blockIdx.x + 3 * NBLK] = 0.f;
}

// ---- tail: only fires when all 10 iterations were active ----
__global__ __launch_bounds__(TPB, 2) void final_kernel(
    const float* __restrict__ buf0, float* __restrict__ out,
    const float* __restrict__ scl0,
    const float* __restrict__ Wout, const int* __restrict__ actArr)
{
  if (actArr[9] == 0) return;
  __shared__ float wot[HH * WOS];
  int t = threadIdx.x;
  stage_wot(Wout, wot, t, TPB);
  __syncthreads();
  int r = blockIdx.x * TPB + t;
  final_write(r, scl0[r], buf0, out, wot);
}

extern "C" void kernel_launch(void* const* d_in, const int* in_sizes, int n_in,
                              void* d_out, int out_size, void* d_ws, size_t ws_size,
                              hipStream_t stream) {
  const int* dirs = (const int*)d_in[0];
  const int* obs = (const int*)d_in[1];
  const float* x = (const float*)d_in[2];
  const float* Wr = (const float*)d_in[3];
  const float* Win = (const float*)d_in[4];
  const float* Wout = (const float*)d_in[5];
  float* out = (float*)d_out;
  float* ws = (float*)d_ws;

  float* buf0 = ws;                              // B*H raw state s0 (then s2,..)
  float* scl0 = ws + (size_t)BB * HH;            // B
  float* scl1 = scl0 + BB;                       // B
  float* partials = scl1 + BB;                   // NBF (gate for "current" iteration)
  float* partials0 = partials + NBF;             // NBF (gate0)
  int* actArr = (int*)(partials0 + NBF);         // 16 ints
  float* buf1 = out + (size_t)BB * NOB;          // s-slice of d_out: s1 (normalized)

  fused_kernel<<<NBF, TPB, 0, stream>>>(x, dirs, obs, Wr, Wout, Win,
                                        buf0, buf1, scl0, scl1, partials0, partials, out);
  resolve_kernel<<<NBLK, TPB, 0, stream>>>(buf0, buf1, scl0, scl1, Wr, Wout, Win,
                                           dirs, obs, partials0, partials, actArr, out);
  for (int k = 2; k < 10; ++k)
    step_kernel<<<NBLK, TPB, 0, stream>>>(buf0, buf1, scl0, scl1,
                                          Wr, Wout, Win, dirs, obs, partials, actArr, out, k);
  final_kernel<<<NBLK, TPB, 0, stream>>>(buf0, out, scl0, Wout, actArr);
}

// Round 23
// 86.211 us; speedup vs baseline: 1.4139x; 1.4139x over previous
//
#include <hip/hip_runtime.h>
#include <math.h>

#define BB 131072
#define HH 64
#define NOB 32
#define NDIRS 8
#define LR_IT 1e-3f
#define TOLV 1e-3f
#define EPSV 1e-6f
#define NBLK 512
#define NBF  2048      // fused grid (64 rows/block)
#define RPB  64
#define TPB 256
#define WRS 68
#define WOS 36
#define INV_BH (1.0f/8388608.0f)

typedef _Float16 f16x8 __attribute__((ext_vector_type(8)));
typedef float f32x4v __attribute__((ext_vector_type(4)));

// ---------------- legacy helpers (resolve/step/final, proven r11 bodies) --------------
#define D16(pp, Wp, b) ((pp).x*(Wp)[(b)+0] + (pp).y*(Wp)[(b)+1] + (pp).z*(Wp)[(b)+2] + (pp).w*(Wp)[(b)+3])
#define DOT64P(Wp) (D16(p0,Wp,0)+D16(p1,Wp,4)+D16(p2,Wp,8)+D16(p3,Wp,12)+ \
                    D16(p4,Wp,16)+D16(p5,Wp,20)+D16(p6,Wp,24)+D16(p7,Wp,28)+ \
                    D16(p8,Wp,32)+D16(p9,Wp,36)+D16(p10,Wp,40)+D16(p11,Wp,44)+ \
                    D16(p12,Wp,48)+D16(p13,Wp,52)+D16(p14,Wp,56)+D16(p15,Wp,60))
#define LOADP(src) \
  float4 p0=(src)[0], p1=(src)[1], p2=(src)[2], p3=(src)[3], \
         p4=(src)[4], p5=(src)[5], p6=(src)[6], p7=(src)[7], \
         p8=(src)[8], p9=(src)[9], p10=(src)[10], p11=(src)[11], \
         p12=(src)[12], p13=(src)[13], p14=(src)[14], p15=(src)[15];
#define SUMSQ4(pp) ((pp).x*(pp).x + (pp).y*(pp).y + (pp).z*(pp).z + (pp).w*(pp).w)
#define SUM4(pp) ((pp).x + (pp).y + (pp).z + (pp).w)

__device__ __forceinline__ void stage_wr(const float* __restrict__ Wr, float* wrl, int t, int bs) {
  const float4* g = (const float4*)Wr;
  for (int i = t; i < 1024; i += bs) {
    int h = i >> 4, k4 = i & 15;
    *(float4*)&wrl[h * WRS + k4 * 4] = g[i];
  }
}
__device__ __forceinline__ void stage_wot(const float* __restrict__ Wout, float* wot, int t, int bs) {
  for (int i = t; i < NOB * HH; i += bs) {
    int o = i >> 6, h = i & 63;
    wot[h * WOS + o] = Wout[i];
  }
}
__device__ __forceinline__ void stage_wint(const float* __restrict__ Win, float* wint, int t, int bs) {
  for (int i = t; i < HH * NDIRS; i += bs) {
    int h = i >> 3, d = i & 7;
    wint[d * WRS + h] = Win[i];
  }
}

__device__ __forceinline__ float block_reduce_all(float v, float* red, int t) {
  #pragma unroll
  for (int off = 32; off > 0; off >>= 1) v += __shfl_down(v, off);
  __syncthreads();
  if ((t & 63) == 0) red[t >> 6] = v;
  __syncthreads();
  return red[0] + red[1] + red[2] + red[3];
}

// reduce the NBF-entry gate array with a 256-thread block
__device__ __forceinline__ float gate_reduce_nbf(const float* __restrict__ p, float* red, int t) {
  float v = 0.f;
  #pragma unroll
  for (int j = 0; j < NBF / TPB; ++j) v += p[t + TPB * j];
  return block_reduce_all(v, red, t);
}

#define SOFTJP(zzp, a_sv, obv) { \
  float m_ = -1e30f; \
  _Pragma("unroll") for (int o_=0;o_<NOB;++o_) m_ = fmaxf(m_, (zzp)[o_]); \
  float se_ = 0.f; \
  _Pragma("unroll") for (int o_=0;o_<NOB;++o_){ (zzp)[o_]=__expf((a_sv)*((zzp)[o_]-m_)); se_+=(zzp)[o_];} \
  float rse_ = 1.f/se_; float fob_=0.f, sf2_=0.f; \
  _Pragma("unroll") for (int o_=0;o_<NOB;++o_){ float f_=(zzp)[o_]*rse_; (zzp)[o_]=f_; sf2_+=f_*f_; fob_ += (o_==(obv))?f_:0.f;} \
  float fe_ = fob_ - sf2_; \
  _Pragma("unroll") for (int o_=0;o_<NOB;++o_){ float ep_=((o_==(obv))?1.f:0.f)-(zzp)[o_]; (zzp)[o_]=(zzp)[o_]*(ep_-fe_);} }

__device__ __forceinline__ void final_write(
    int r, float a_s, const float* __restrict__ S, float* __restrict__ out,
    const float* wot) {
  const float4* __restrict__ sr4 = (const float4*)(S + (size_t)r * HH);
  float zz[NOB];
  #pragma unroll
  for (int o = 0; o < NOB; ++o) zz[o] = 0.f;
  #pragma unroll 1
  for (int h0 = 0; h0 < 16; ++h0) {
    float4 s4 = sr4[h0];
    const float* t0 = &wot[(h0 * 4 + 0) * WOS];
    const float* t1 = &wot[(h0 * 4 + 1) * WOS];
    const float* t2 = &wot[(h0 * 4 + 2) * WOS];
    const float* t3 = &wot[(h0 * 4 + 3) * WOS];
    #pragma unroll
    for (int o = 0; o < NOB; ++o)
      zz[o] += s4.x * t0[o] + s4.y * t1[o] + s4.z * t2[o] + s4.w * t3[o];
  }
  float m = -1e30f;
  #pragma unroll
  for (int o = 0; o < NOB; ++o) m = fmaxf(m, zz[o]);
  float se = 0.f;
  #pragma unroll
  for (int o = 0; o < NOB; ++o) { zz[o] = __expf(a_s * (zz[o] - m)); se += zz[o]; }
  float rse = 1.f / se;

  float4* po = (float4*)(out + (size_t)r * NOB);
  #pragma unroll
  for (int o4 = 0; o4 < 8; ++o4) {
    float4 f;
    f.x = zz[o4 * 4 + 0] * rse; f.y = zz[o4 * 4 + 1] * rse;
    f.z = zz[o4 * 4 + 2] * rse; f.w = zz[o4 * 4 + 3] * rse;
    po[o4] = f;
  }
  float4* so = (float4*)(out + (size_t)BB * NOB + (size_t)r * HH);
  #pragma unroll 1
  for (int h0 = 0; h0 < 16; ++h0) {
    float4 s4 = sr4[h0];
    s4.x *= a_s; s4.y *= a_s; s4.z *= a_s; s4.w *= a_s;
    so[h0] = s4;
  }
}

// ---- helper: load 8 consecutive f32 -> f16x8 fragment ----
__device__ __forceinline__ f16x8 ldb8(const float* __restrict__ p) {
  float4 a = *(const float4*)p;
  float4 b = *(const float4*)(p + 4);
  f16x8 r;
  r[0]=(_Float16)a.x; r[1]=(_Float16)a.y; r[2]=(_Float16)a.z; r[3]=(_Float16)a.w;
  r[4]=(_Float16)b.x; r[5]=(_Float16)b.y; r[6]=(_Float16)b.z; r[7]=(_Float16)b.w;
  return r;
}
// load 8 f32 at stride (in floats) from LDS -> f16x8 fragment (column gather)
__device__ __forceinline__ f16x8 ldb8s(const float* p, int stride) {
  f16x8 r;
  #pragma unroll
  for (int i = 0; i < 8; ++i) r[i] = (_Float16)p[i * stride];
  return r;
}

#define MFMA16(a, b, c) __builtin_amdgcn_mfma_f32_16x16x32_f16((a), (b), (c), 0, 0, 0)

// ---- fused (MFMA): init + iteration-0 candidate + SPECULATIVE final output ----
// 1 wave = 16 rows, 4 waves/block; launch_bounds(.,4) = proven no-spill config.
__global__ __launch_bounds__(TPB, 4) void fused_kernel(
    const float* __restrict__ x, const int* __restrict__ dirs,
    const int* __restrict__ obs,
    const float* __restrict__ Wr, const float* __restrict__ Wout,
    const float* __restrict__ Win,
    float* __restrict__ buf0, float* __restrict__ buf1,
    float* __restrict__ scl0, float* __restrict__ scl1,
    float* __restrict__ partials0, float* __restrict__ partials1,
    float* __restrict__ out)
{
  __shared__ float s0sh[4 * 16 * 68];
  __shared__ float jpsh[4 * 16 * 36];
  __shared__ float red0[4], red1[4];
  int t = threadIdx.x;
  int w = t >> 6, l = t & 63;
  int l15 = l & 15, lg = l >> 4;
  int rbase = blockIdx.x * RPB + w * 16;
  float* s0l = &s0sh[w * 16 * 68];
  float* jpl = &jpsh[w * 16 * 36];

  // ---- stage Wout into s0sh (padded stride 66 -> bank-spread column gathers) ----
  for (int i = t; i < NOB * HH; i += TPB) {
    int o = i >> 6, h = i & 63;
    s0sh[o * 66 + h] = Wout[i];
  }

  // ---- contiguous global B-fragments (overlap the staging latency) ----
  f16x8 bWr[4][2];
  #pragma unroll
  for (int T = 0; T < 4; ++T)
    #pragma unroll
    for (int c = 0; c < 2; ++c)
      bWr[T][c] = ldb8(Wr + (size_t)(16*T + l15) * HH + 32*c + lg*8);
  f16x8 bWo[2][2];
  #pragma unroll
  for (int T = 0; T < 2; ++T)
    #pragma unroll
    for (int c = 0; c < 2; ++c)
      bWo[T][c] = ldb8(Wout + (size_t)(16*T + l15) * HH + 32*c + lg*8);

  __syncthreads();   // staged Wout visible
  // GEMM3 B[k=o][j=h]: element i -> Wout[(lg*8+i)][16T+l15] from LDS (stride 66)
  f16x8 bWt[4];
  #pragma unroll
  for (int T = 0; T < 4; ++T)
    bWt[T] = ldb8s(s0sh + (lg*8) * 66 + 16*T + l15, 66);
  __syncthreads();   // s0sh released for reuse as the s0 tile

  // ---- phase 1: x A-frags + row stats ----
  const float4* __restrict__ xr = (const float4*)(x + (size_t)(rbase + l15) * HH);
  float4 xa0 = xr[lg*2],     xa1 = xr[lg*2 + 1];
  float4 xb0 = xr[8 + lg*2], xb1 = xr[8 + lg*2 + 1];
  f16x8 ax0, ax1;
  {
    f16x8 r;
    r[0]=(_Float16)xa0.x; r[1]=(_Float16)xa0.y; r[2]=(_Float16)xa0.z; r[3]=(_Float16)xa0.w;
    r[4]=(_Float16)xa1.x; r[5]=(_Float16)xa1.y; r[6]=(_Float16)xa1.z; r[7]=(_Float16)xa1.w;
    ax0 = r;
    r[0]=(_Float16)xb0.x; r[1]=(_Float16)xb0.y; r[2]=(_Float16)xb0.z; r[3]=(_Float16)xb0.w;
    r[4]=(_Float16)xb1.x; r[5]=(_Float16)xb1.y; r[6]=(_Float16)xb1.z; r[7]=(_Float16)xb1.w;
    ax1 = r;
  }
  float ssx = SUMSQ4(xa0)+SUMSQ4(xa1)+SUMSQ4(xb0)+SUMSQ4(xb1);
  float sx  = SUM4(xa0)+SUM4(xa1)+SUM4(xb0)+SUM4(xb1);
  ssx += __shfl_xor(ssx, 16); ssx += __shfl_xor(ssx, 32);
  sx  += __shfl_xor(sx, 16);  sx  += __shfl_xor(sx, 32);
  float inv_x = 1.f / (sqrtf(ssx) + EPSV);   // row l15

  // ---- GEMM1 ----
  f32x4v acc[4];
  #pragma unroll
  for (int T = 0; T < 4; ++T) {
    f32x4v c = {0.f, 0.f, 0.f, 0.f};
    c = MFMA16(ax0, bWr[T][0], c);
    c = MFMA16(ax1, bWr[T][1], c);
    acc[T] = c;
  }

  // ---- phase 3: s0 = relu(inv_x*acc + drive) ----
  float invxr[4], sxr[4];
  int dirr[4], obr[4];
  #pragma unroll
  for (int reg = 0; reg < 4; ++reg) {
    invxr[reg] = __shfl(inv_x, 4*lg + reg);
    sxr[reg]   = __shfl(sx,    4*lg + reg);
    dirr[reg]  = dirs[rbase + 4*lg + reg];
    obr[reg]   = obs [rbase + 4*lg + reg];
  }
  float s0v[4][4];    // [T][reg]
  float ssg[4] = {0.f,0.f,0.f,0.f}, sgv[4] = {0.f,0.f,0.f,0.f};
  #pragma unroll
  for (int T = 0; T < 4; ++T)
    #pragma unroll
    for (int reg = 0; reg < 4; ++reg) {
      float drive = Win[(size_t)(16*T + l15) * NDIRS + dirr[reg]];
      float v = fmaxf(fmaf(invxr[reg], acc[T][reg], drive), 0.f);
      s0v[T][reg] = v;
      ssg[reg] += v * v; sgv[reg] += v;
    }
  #pragma unroll
  for (int reg = 0; reg < 4; ++reg) {
    #pragma unroll
    for (int m = 1; m < 16; m <<= 1) {
      ssg[reg] += __shfl_xor(ssg[reg], m);
      sgv[reg] += __shfl_xor(sgv[reg], m);
    }
  }
  float invg[4];
  #pragma unroll
  for (int reg = 0; reg < 4; ++reg) invg[reg] = 1.f / (sqrtf(ssg[reg]) + EPSV);
  if (l15 == 0) {
    #pragma unroll
    for (int reg = 0; reg < 4; ++reg) scl0[rbase + 4*lg + reg] = invg[reg];
  }
  float g0 = 0.f;
  if (l15 == 0) {
    #pragma unroll
    for (int reg = 0; reg < 4; ++reg)
      g0 += invxr[reg] * sxr[reg] - invg[reg] * sgv[reg];
  }

  // s0 -> LDS tile ; coalesced buf0 write
  #pragma unroll
  for (int T = 0; T < 4; ++T)
    #pragma unroll
    for (int reg = 0; reg < 4; ++reg)
      s0l[(4*lg + reg) * 68 + 16*T + l15] = s0v[T][reg];
  {
    int rr = l >> 2, cc = (l & 3) * 16;
    const float4* srcl = (const float4*)(s0l + rr * 68 + cc);
    float4* dst = (float4*)(buf0 + (size_t)(rbase + rr) * HH + cc);
    dst[0] = srcl[0]; dst[1] = srcl[1]; dst[2] = srcl[2]; dst[3] = srcl[3];
  }

  // ---- GEMM2: logits = s0 @ WoutT ----
  f16x8 as0, as1;
  {
    const float* pr = s0l + l15 * 68 + lg * 8;
    as0 = ldb8(pr);
    as1 = ldb8(pr + 32);
  }
  f32x4v lac[2];
  #pragma unroll
  for (int T = 0; T < 2; ++T) {
    f32x4v c = {0.f, 0.f, 0.f, 0.f};
    c = MFMA16(as0, bWo[T][0], c);
    c = MFMA16(as1, bWo[T][1], c);
    lac[T] = c;
  }

  // ---- phase 5: softmax + jacobian per row ----
  float jp0[4], jp1[4];
  #pragma unroll
  for (int reg = 0; reg < 4; ++reg) {
    float z0 = lac[0][reg], z1 = lac[1][reg];
    float m = fmaxf(z0, z1);
    #pragma unroll
    for (int mm = 1; mm < 16; mm <<= 1) m = fmaxf(m, __shfl_xor(m, mm));
    float e0 = __expf(invg[reg] * (z0 - m));
    float e1 = __expf(invg[reg] * (z1 - m));
    float se = e0 + e1;
    #pragma unroll
    for (int mm = 1; mm < 16; mm <<= 1) se += __shfl_xor(se, mm);
    float rse = 1.f / se;
    float f0 = e0 * rse, f1 = e1 * rse;
    int ob = obr[reg];
    float on0 = (l15 == ob) ? 1.f : 0.f;
    float on1 = (16 + l15 == ob) ? 1.f : 0.f;
    float fob = on0 * f0 + on1 * f1;
    float sf2 = f0 * f0 + f1 * f1;
    #pragma unroll
    for (int mm = 1; mm < 16; mm <<= 1) {
      fob += __shfl_xor(fob, mm);
      sf2 += __shfl_xor(sf2, mm);
    }
    float fe = fob - sf2;
    jp0[reg] = f0 * (on0 - f0 - fe);
    jp1[reg] = f1 * (on1 - f1 - fe);
  }

  #pragma unroll
  for (int reg = 0; reg < 4; ++reg) {
    jpl[(4*lg + reg) * 36 + l15]      = jp0[reg];
    jpl[(4*lg + reg) * 36 + 16 + l15] = jp1[reg];
  }
  f16x8 ajp;
  {
    const float* pr = jpl + l15 * 36 + lg * 8;
    ajp = ldb8(pr);
  }

  // ---- GEMM3: pv = jp @ Wout ----
  f32x4v pv[4];
  #pragma unroll
  for (int T = 0; T < 4; ++T) {
    f32x4v c = {0.f, 0.f, 0.f, 0.f};
    pv[T] = MFMA16(ajp, bWt[T], c);
  }

  // ---- phase 8: s1 = sv + LR*(s0 - sv + pv); normalize IN PLACE; gates ----
  float ssu[4] = {0.f,0.f,0.f,0.f}, suv[4] = {0.f,0.f,0.f,0.f};
  #pragma unroll
  for (int T = 0; T < 4; ++T)
    #pragma unroll
    for (int reg = 0; reg < 4; ++reg) {
      float s0_ = s0v[T][reg];
      float sv = invg[reg] * s0_;
      float u = fmaf(LR_IT, s0_ - sv + pv[T][reg], sv);
      s0v[T][reg] = u;            // raw s1
      ssu[reg] += u * u; suv[reg] += u;
    }
  #pragma unroll
  for (int reg = 0; reg < 4; ++reg) {
    #pragma unroll
    for (int m = 1; m < 16; m <<= 1) {
      ssu[reg] += __shfl_xor(ssu[reg], m);
      suv[reg] += __shfl_xor(suv[reg], m);
    }
  }
  float invu[4];
  #pragma unroll
  for (int reg = 0; reg < 4; ++reg) invu[reg] = 1.f / (sqrtf(ssu[reg]) + EPSV);
  // buf1 holds NORMALIZED s1 -> effective downstream scale is 1.0
  if (l15 == 0) {
    #pragma unroll
    for (int reg = 0; reg < 4; ++reg) scl1[rbase + 4*lg + reg] = 1.0f;
  }
  float g1 = 0.f;
  if (l15 == 0) {
    #pragma unroll
    for (int reg = 0; reg < 4; ++reg)
      g1 += invg[reg] * sgv[reg] - invu[reg] * suv[reg];
  }
  #pragma unroll
  for (int T = 0; T < 4; ++T)
    #pragma unroll
    for (int reg = 0; reg < 4; ++reg)
      s0v[T][reg] *= invu[reg];   // normalized s1

  // normalized s1 -> LDS tile -> coalesced buf1 (= out s-slice) write
  #pragma unroll
  for (int T = 0; T < 4; ++T)
    #pragma unroll
    for (int reg = 0; reg < 4; ++reg)
      s0l[(4*lg + reg) * 68 + 16*T + l15] = s0v[T][reg];
  {
    int rr = l >> 2, cc = (l & 3) * 16;
    const float4* srcl = (const float4*)(s0l + rr * 68 + cc);
    float4* dst = (float4*)(buf1 + (size_t)(rbase + rr) * HH + cc);
    dst[0] = srcl[0]; dst[1] = srcl[1]; dst[2] = srcl[2]; dst[3] = srcl[3];
  }

  // ---- speculative final: preds = softmax(s1n @ WoutT) -> out[:B*32] ----
  {
    const float* pr = s0l + l15 * 68 + lg * 8;
    f16x8 a0 = ldb8(pr);
    f16x8 a1 = ldb8(pr + 32);
    f32x4v pl0 = {0.f,0.f,0.f,0.f}, pl1 = {0.f,0.f,0.f,0.f};
    pl0 = MFMA16(a0, bWo[0][0], pl0); pl0 = MFMA16(a1, bWo[0][1], pl0);
    pl1 = MFMA16(a0, bWo[1][0], pl1); pl1 = MFMA16(a1, bWo[1][1], pl1);
    #pragma unroll
    for (int reg = 0; reg < 4; ++reg) {
      float z0 = pl0[reg], z1 = pl1[reg];
      float m = fmaxf(z0, z1);
      #pragma unroll
      for (int mm = 1; mm < 16; mm <<= 1) m = fmaxf(m, __shfl_xor(m, mm));
      float e0 = __expf(z0 - m), e1 = __expf(z1 - m);
      float se = e0 + e1;
      #pragma unroll
      for (int mm = 1; mm < 16; mm <<= 1) se += __shfl_xor(se, mm);
      float rse = 1.f / se;
      jpl[(4*lg + reg) * 36 + l15]      = e0 * rse;
      jpl[(4*lg + reg) * 36 + 16 + l15] = e1 * rse;
    }
    int rr = l >> 2, cc = (l & 3) * 8;
    const float4* srcl = (const float4*)(jpl + rr * 36 + cc);
    float4* dst = (float4*)(out + (size_t)(rbase + rr) * NOB + cc);
    dst[0] = srcl[0]; dst[1] = srcl[1];
  }

  // ---- gates: wave totals -> block totals ----
  g0 += __shfl_xor(g0, 16); g0 += __shfl_xor(g0, 32);
  g1 += __shfl_xor(g1, 16); g1 += __shfl_xor(g1, 32);
  if (l == 0) { red0[w] = g0; red1[w] = g1; }
  __syncthreads();
  if (t == 0) {
    partials0[blockIdx.x] = red0[0] + red0[1] + red0[2] + red0[3];
    partials1[blockIdx.x] = red1[0] + red1[1] + red1[2] + red1[3];
  }
}

// ---- resolve: decide act0/act1; expected path is a no-op (fused wrote output) ----
__global__ __launch_bounds__(TPB, 2) void resolve_kernel(
    float* __restrict__ buf0, float* __restrict__ buf1,
    float* __restrict__ scl0, float* __restrict__ scl1,
    const float* __restrict__ Wr, const float* __restrict__ Wout,
    const float* __restrict__ Win,
    const int* __restrict__ dirs, const int* __restrict__ obs,
    const float* __restrict__ partials0, float* __restrict__ partials,
    int* __restrict__ actArr, float* __restrict__ out)
{
  __shared__ float wrl[HH * WRS];
  __shared__ float wot[HH * WOS];
  __shared__ float wint[NDIRS * WRS];
  __shared__ float red[4];
  int t = threadIdx.x;

  float t0v = gate_reduce_nbf(partials0, red, t);
  int act0 = (fabsf(t0v * INV_BH) > TOLV) ? 1 : 0;
  float t1v = gate_reduce_nbf(partials, red, t);
  int act1 = (fabsf(t1v * INV_BH) > TOLV) ? 1 : 0;
  if (blockIdx.x == 0 && t == 0) actArr[1] = act0 && act1;

  int r = blockIdx.x * TPB + t;

  if (!act0) {
    // iteration 0 inactive: final = s0 (overwrite speculative s1 output)
    if (t < 4) partials[blockIdx.x * 4 + t] = partials0[blockIdx.x * 4 + t];
    stage_wot(Wout, wot, t, TPB);
    __syncthreads();
    final_write(r, scl0[r], buf0, out, wot);
    return;
  }
  if (!act1) return;   // EXPECTED PATH: fused already wrote preds + normalized s1

  // both active: run iteration 1 fully. S=buf1 (normalized, scl1==1), P=buf0, W=buf0/scl0.
  stage_wr(Wr, wrl, t, TPB);
  stage_wot(Wout, wot, t, TPB);
  stage_wint(Win, wint, t, TPB);
  __syncthreads();

  float a_s = scl1[r];
  float a_p = scl0[r];
  int ob = obs[r];
  int dir = dirs[r];
  const float4* __restrict__ sr4 = (const float4*)(buf1 + (size_t)r * HH);

  float zz[NOB];
  #pragma unroll
  for (int o = 0; o < NOB; ++o) zz[o] = 0.f;
  float sS = 0.f;
  #pragma unroll 1
  for (int h0 = 0; h0 < 16; ++h0) {
    float4 s4 = sr4[h0];
    sS += SUM4(s4);
    const float* t0 = &wot[(h0 * 4 + 0) * WOS];
    const float* t1 = &wot[(h0 * 4 + 1) * WOS];
    const float* t2 = &wot[(h0 * 4 + 2) * WOS];
    const float* t3 = &wot[(h0 * 4 + 3) * WOS];
    #pragma unroll
    for (int o = 0; o < NOB; ++o)
      zz[o] += s4.x * t0[o] + s4.y * t1[o] + s4.z * t2[o] + s4.w * t3[o];
  }
  SOFTJP(zz, a_s, ob)
  __syncthreads();   // live-range firewall

  const float4* __restrict__ pr4 = (const float4*)(buf0 + (size_t)r * HH);
  LOADP(pr4);
  float4* wo4 = (float4*)(buf0 + (size_t)r * HH);
  float ssu = 0.f, su = 0.f;
#define STEP_C_ONE(JJ, COMP) { \
    const float* wr_ = &wrl[(h0 * 4 + JJ) * WRS]; \
    float g_ = fmaxf(fmaf(a_p, DOT64P(wr_), d4.COMP), 0.f); \
    const float* wt_ = &wot[(h0 * 4 + JJ) * WOS]; \
    float w_ = 0.f; \
    _Pragma("unroll") \
    for (int o = 0; o < NOB; ++o) w_ += zz[o] * wt_[o]; \
    float sv_ = a_s * s4.COMP; \
    float uu_ = fmaf(LR_IT, g_ - sv_ + w_, sv_); \
    u.COMP = uu_; ssu += uu_ * uu_; su += uu_; }
  #pragma unroll 1
  for (int h0 = 0; h0 < 16; ++h0) {
    float4 s4 = sr4[h0];
    float4 d4 = *(const float4*)&wint[dir * WRS + h0 * 4];
    float4 u;
    STEP_C_ONE(0, x) STEP_C_ONE(1, y) STEP_C_ONE(2, z) STEP_C_ONE(3, w)
    wo4[h0] = u;
  }
  float inv_u = 1.f / (sqrtf(ssu) + EPSV);
  scl0[r] = inv_u;

  float tot2 = block_reduce_all(a_s * sS - inv_u * su, red, t);
  if (t == 0) partials[blockIdx.x] = tot2;
  if (t == 1) partials[blockIdx.x + NBLK] = 0.f;
  if (t == 2) partials[blockIdx.x + 2 * NBLK] = 0.f;
  if (t == 3) partials[blockIdx.x + 3 * NBLK] = 0.f;
}

// ---- generic step k>=2: gate + (active | first-inactive final | no-op) ----
__global__ __launch_bounds__(TPB, 2) void step_kernel(
    float* __restrict__ buf0, float* __restrict__ buf1,
    float* __restrict__ scl0, float* __restrict__ scl1,
    const float* __restrict__ Wr, const float* __restrict__ Wout,
    const float* __restrict__ Win,
    const int* __restrict__ dirs, const int* __restrict__ obs,
    float* __restrict__ partials, int* __restrict__ actArr,
    float* __restrict__ out, int k)
{
  __shared__ float red[4];
  __shared__ float wrl[HH * WRS];
  __shared__ float wot[HH * WOS];
  __shared__ float wint[NDIRS * WRS];
  int t = threadIdx.x;

  float tot = gate_reduce_nbf(partials, red, t);
  int active = (fabsf(tot * INV_BH) > TOLV) ? 1 : 0;
  if (blockIdx.x == 0 && t == 0) actArr[k] = active;

  int si = k & 1;
  int r = blockIdx.x * TPB + t;

  if (!active) {
    int first_inactive = actArr[k - 1];
    if (!first_inactive) return;
    stage_wot(Wout, wot, t, TPB);
    __syncthreads();
    const float* S   = si ? buf1 : buf0;
    const float* scl = si ? scl1 : scl0;
    final_write(r, scl[r], S, out, wot);
    return;
  }

  const float* S    = si ? buf1 : buf0;
  const float* sclS = si ? scl1 : scl0;
  float* W          = si ? buf0 : buf1;
  float* sclW       = si ? scl0 : scl1;

  stage_wr(Wr, wrl, t, TPB);
  stage_wot(Wout, wot, t, TPB);
  stage_wint(Win, wint, t, TPB);
  __syncthreads();

  float a_s = sclS[r];
  float a_p = sclW[r];
  int ob = obs[r];
  int dir = dirs[r];
  const float4* __restrict__ sr4 = (const float4*)(S + (size_t)r * HH);

  float zz[NOB];
  #pragma unroll
  for (int o = 0; o < NOB; ++o) zz[o] = 0.f;
  float sS = 0.f;
  #pragma unroll 1
  for (int h0 = 0; h0 < 16; ++h0) {
    float4 s4 = sr4[h0];
    sS += SUM4(s4);
    const float* t0 = &wot[(h0 * 4 + 0) * WOS];
    const float* t1 = &wot[(h0 * 4 + 1) * WOS];
    const float* t2 = &wot[(h0 * 4 + 2) * WOS];
    const float* t3 = &wot[(h0 * 4 + 3) * WOS];
    #pragma unroll
    for (int o = 0; o < NOB; ++o)
      zz[o] += s4.x * t0[o] + s4.y * t1[o] + s4.z * t2[o] + s4.w * t3[o];
  }
  SOFTJP(zz, a_s, ob)
  __syncthreads();

  const float4* __restrict__ pr4 = (const float4*)(W + (size_t)r * HH);
  LOADP(pr4);
  float4* wo4 = (float4*)(W + (size_t)r * HH);
  float ssu = 0.f, su = 0.f;
  #pragma unroll 1
  for (int h0 = 0; h0 < 16; ++h0) {
    float4 s4 = sr4[h0];
    float4 d4 = *(const float4*)&wint[dir * WRS + h0 * 4];
    float4 u;
    STEP_C_ONE(0, x) STEP_C_ONE(1, y) STEP_C_ONE(2, z) STEP_C_ONE(3, w)
    wo4[h0] = u;
  }
  float inv_u = 1.f / (sqrtf(ssu) + EPSV);
  sclW[r] = inv_u;

  float tot2 = block_reduce_all(a_s * sS - inv_u * su, red, t);
  if (t == 0) partials[blockIdx.x] = tot2;
  if (t == 1) partials[blockIdx.x + NBLK] = 0.f;
  if (t == 2) partials[blockIdx.x + 2 * NBLK] = 0.f;
  if (t == 3) partials[blockIdx.x + 3 * NBLK] = 0.f;
}

// ---- tail: only fires when all 10 iterations were active ----
__global__ __launch_bounds__(TPB, 2) void final_kernel(
    const float* __restrict__ buf0, float* __restrict__ out,
    const float* __restrict__ scl0,
    const float* __restrict__ Wout, const int* __restrict__ actArr)
{
  if (actArr[9] == 0) return;
  __shared__ float wot[HH * WOS];
  int t = threadIdx.x;
  stage_wot(Wout, wot, t, TPB);
  __syncthreads();
  int r = blockIdx.x * TPB + t;
  final_write(r, scl0[r], buf0, out, wot);
}

extern "C" void kernel_launch(void* const* d_in, const int* in_sizes, int n_in,
                              void* d_out, int out_size, void* d_ws, size_t ws_size,
                              hipStream_t stream) {
  const int* dirs = (const int*)d_in[0];
  const int* obs = (const int*)d_in[1];
  const float* x = (const float*)d_in[2];
  const float* Wr = (const float*)d_in[3];
  const float* Win = (const float*)d_in[4];
  const float* Wout = (const float*)d_in[5];
  float* out = (float*)d_out;
  float* ws = (float*)d_ws;

  float* buf0 = ws;                              // B*H raw state s0 (then s2,..)
  float* scl0 = ws + (size_t)BB * HH;            // B
  float* scl1 = scl0 + BB;                       // B
  float* partials = scl1 + BB;                   // NBF (gate for "current" iteration)
  float* partials0 = partials + NBF;             // NBF (gate0)
  int* actArr = (int*)(partials0 + NBF);         // 16 ints
  float* buf1 = out + (size_t)BB * NOB;          // s-slice of d_out: s1 (normalized)

  fused_kernel<<<NBF, TPB, 0, stream>>>(x, dirs, obs, Wr, Wout, Win,
                                        buf0, buf1, scl0, scl1, partials0, partials, out);
  resolve_kernel<<<NBLK, TPB, 0, stream>>>(buf0, buf1, scl0, scl1, Wr, Wout, Win,
                                           dirs, obs, partials0, partials, actArr, out);
  for (int k = 2; k < 10; ++k)
    step_kernel<<<NBLK, TPB, 0, stream>>>(buf0, buf1, scl0, scl1,
                                          Wr, Wout, Win, dirs, obs, partials, actArr, out, k);
  final_kernel<<<NBLK, TPB, 0, stream>>>(buf0, out, scl0, Wout, actArr);
}

// Round 24
// 82.018 us; speedup vs baseline: 1.4862x; 1.0511x over previous
//
#include <hip/hip_runtime.h>
#include <math.h>

#define BB 131072
#define HH 64
#define NOB 32
#define NDIRS 8
#define LR_IT 1e-3f
#define TOLV 1e-3f
#define EPSV 1e-6f
#define NBLK 512
#define NBF  2048      // fused grid (64 rows/block)
#define RPB  64
#define TPB 256
#define WRS 68
#define WOS 36
#define INV_BH (1.0f/8388608.0f)

typedef _Float16 f16x8 __attribute__((ext_vector_type(8)));
typedef float f32x4v __attribute__((ext_vector_type(4)));

// ---------------- legacy helpers (resolve/step/final, proven r11 bodies) --------------
#define D16(pp, Wp, b) ((pp).x*(Wp)[(b)+0] + (pp).y*(Wp)[(b)+1] + (pp).z*(Wp)[(b)+2] + (pp).w*(Wp)[(b)+3])
#define DOT64P(Wp) (D16(p0,Wp,0)+D16(p1,Wp,4)+D16(p2,Wp,8)+D16(p3,Wp,12)+ \
                    D16(p4,Wp,16)+D16(p5,Wp,20)+D16(p6,Wp,24)+D16(p7,Wp,28)+ \
                    D16(p8,Wp,32)+D16(p9,Wp,36)+D16(p10,Wp,40)+D16(p11,Wp,44)+ \
                    D16(p12,Wp,48)+D16(p13,Wp,52)+D16(p14,Wp,56)+D16(p15,Wp,60))
#define LOADP(src) \
  float4 p0=(src)[0], p1=(src)[1], p2=(src)[2], p3=(src)[3], \
         p4=(src)[4], p5=(src)[5], p6=(src)[6], p7=(src)[7], \
         p8=(src)[8], p9=(src)[9], p10=(src)[10], p11=(src)[11], \
         p12=(src)[12], p13=(src)[13], p14=(src)[14], p15=(src)[15];
#define SUMSQ4(pp) ((pp).x*(pp).x + (pp).y*(pp).y + (pp).z*(pp).z + (pp).w*(pp).w)
#define SUM4(pp) ((pp).x + (pp).y + (pp).z + (pp).w)

__device__ __forceinline__ void stage_wr(const float* __restrict__ Wr, float* wrl, int t, int bs) {
  const float4* g = (const float4*)Wr;
  for (int i = t; i < 1024; i += bs) {
    int h = i >> 4, k4 = i & 15;
    *(float4*)&wrl[h * WRS + k4 * 4] = g[i];
  }
}
__device__ __forceinline__ void stage_wot(const float* __restrict__ Wout, float* wot, int t, int bs) {
  for (int i = t; i < NOB * HH; i += bs) {
    int o = i >> 6, h = i & 63;
    wot[h * WOS + o] = Wout[i];
  }
}
__device__ __forceinline__ void stage_wint(const float* __restrict__ Win, float* wint, int t, int bs) {
  for (int i = t; i < HH * NDIRS; i += bs) {
    int h = i >> 3, d = i & 7;
    wint[d * WRS + h] = Win[i];
  }
}

__device__ __forceinline__ float block_reduce_all(float v, float* red, int t) {
  #pragma unroll
  for (int off = 32; off > 0; off >>= 1) v += __shfl_down(v, off);
  __syncthreads();
  if ((t & 63) == 0) red[t >> 6] = v;
  __syncthreads();
  return red[0] + red[1] + red[2] + red[3];
}

// reduce the NBF-entry gate array with a 256-thread block
__device__ __forceinline__ float gate_reduce_nbf(const float* __restrict__ p, float* red, int t) {
  float v = 0.f;
  #pragma unroll
  for (int j = 0; j < NBF / TPB; ++j) v += p[t + TPB * j];
  return block_reduce_all(v, red, t);
}

#define SOFTJP(zzp, a_sv, obv) { \
  float m_ = -1e30f; \
  _Pragma("unroll") for (int o_=0;o_<NOB;++o_) m_ = fmaxf(m_, (zzp)[o_]); \
  float se_ = 0.f; \
  _Pragma("unroll") for (int o_=0;o_<NOB;++o_){ (zzp)[o_]=__expf((a_sv)*((zzp)[o_]-m_)); se_+=(zzp)[o_];} \
  float rse_ = 1.f/se_; float fob_=0.f, sf2_=0.f; \
  _Pragma("unroll") for (int o_=0;o_<NOB;++o_){ float f_=(zzp)[o_]*rse_; (zzp)[o_]=f_; sf2_+=f_*f_; fob_ += (o_==(obv))?f_:0.f;} \
  float fe_ = fob_ - sf2_; \
  _Pragma("unroll") for (int o_=0;o_<NOB;++o_){ float ep_=((o_==(obv))?1.f:0.f)-(zzp)[o_]; (zzp)[o_]=(zzp)[o_]*(ep_-fe_);} }

__device__ __forceinline__ void final_write(
    int r, float a_s, const float* __restrict__ S, float* __restrict__ out,
    const float* wot) {
  const float4* __restrict__ sr4 = (const float4*)(S + (size_t)r * HH);
  float zz[NOB];
  #pragma unroll
  for (int o = 0; o < NOB; ++o) zz[o] = 0.f;
  #pragma unroll 1
  for (int h0 = 0; h0 < 16; ++h0) {
    float4 s4 = sr4[h0];
    const float* t0 = &wot[(h0 * 4 + 0) * WOS];
    const float* t1 = &wot[(h0 * 4 + 1) * WOS];
    const float* t2 = &wot[(h0 * 4 + 2) * WOS];
    const float* t3 = &wot[(h0 * 4 + 3) * WOS];
    #pragma unroll
    for (int o = 0; o < NOB; ++o)
      zz[o] += s4.x * t0[o] + s4.y * t1[o] + s4.z * t2[o] + s4.w * t3[o];
  }
  float m = -1e30f;
  #pragma unroll
  for (int o = 0; o < NOB; ++o) m = fmaxf(m, zz[o]);
  float se = 0.f;
  #pragma unroll
  for (int o = 0; o < NOB; ++o) { zz[o] = __expf(a_s * (zz[o] - m)); se += zz[o]; }
  float rse = 1.f / se;

  float4* po = (float4*)(out + (size_t)r * NOB);
  #pragma unroll
  for (int o4 = 0; o4 < 8; ++o4) {
    float4 f;
    f.x = zz[o4 * 4 + 0] * rse; f.y = zz[o4 * 4 + 1] * rse;
    f.z = zz[o4 * 4 + 2] * rse; f.w = zz[o4 * 4 + 3] * rse;
    po[o4] = f;
  }
  float4* so = (float4*)(out + (size_t)BB * NOB + (size_t)r * HH);
  #pragma unroll 1
  for (int h0 = 0; h0 < 16; ++h0) {
    float4 s4 = sr4[h0];
    s4.x *= a_s; s4.y *= a_s; s4.z *= a_s; s4.w *= a_s;
    so[h0] = s4;
  }
}

// ---- prep: wotT[h][o] = Wout[o][h]; winT[d][h] = Win[h][d] ----
__global__ __launch_bounds__(TPB) void prep_kernel(
    const float* __restrict__ Wout, const float* __restrict__ Win,
    float* __restrict__ wotT, float* __restrict__ winT)
{
  int t = threadIdx.x;
  for (int i = t; i < NOB * HH; i += TPB) { int h = i >> 5, o = i & 31; wotT[i] = Wout[o * HH + h]; }
  for (int i = t; i < NDIRS * HH; i += TPB) { int d = i >> 6, h = i & 63; winT[i] = Win[h * NDIRS + d]; }
}

// ---- helper: load 8 consecutive f32 -> f16x8 fragment ----
__device__ __forceinline__ f16x8 ldb8(const float* __restrict__ p) {
  float4 a = *(const float4*)p;
  float4 b = *(const float4*)(p + 4);
  f16x8 r;
  r[0]=(_Float16)a.x; r[1]=(_Float16)a.y; r[2]=(_Float16)a.z; r[3]=(_Float16)a.w;
  r[4]=(_Float16)b.x; r[5]=(_Float16)b.y; r[6]=(_Float16)b.z; r[7]=(_Float16)b.w;
  return r;
}

#define MFMA16(a, b, c) __builtin_amdgcn_mfma_f32_16x16x32_f16((a), (b), (c), 0, 0, 0)

// ---- fused (MFMA): init + iteration-0 candidate + SPECULATIVE final output ----
// 1 wave = 16 rows, 4 waves/block, launch_bounds(.,4): proven no-spill config.
__global__ __launch_bounds__(TPB, 4) void fused_kernel(
    const float* __restrict__ x, const int* __restrict__ dirs,
    const int* __restrict__ obs,
    const float* __restrict__ Wr, const float* __restrict__ Wout,
    const float* __restrict__ wotT, const float* __restrict__ winT,
    float* __restrict__ buf0, float* __restrict__ buf1,
    float* __restrict__ scl0, float* __restrict__ scl1,
    float* __restrict__ partials0, float* __restrict__ partials1,
    float* __restrict__ out)
{
  __shared__ float s0sh[4 * 16 * 68];
  __shared__ float jpsh[4 * 16 * 36];
  __shared__ float red0[4], red1[4];
  int t = threadIdx.x;
  int w = t >> 6, l = t & 63;
  int l15 = l & 15, lg = l >> 4;
  int rbase = blockIdx.x * RPB + w * 16;
  float* s0l = &s0sh[w * 16 * 68];
  float* jpl = &jpsh[w * 16 * 36];

  // ---- B-fragments (VGPR-resident for the whole kernel; all coalesced rows) ----
  f16x8 bWr[4][2];
  #pragma unroll
  for (int T = 0; T < 4; ++T)
    #pragma unroll
    for (int c = 0; c < 2; ++c)
      bWr[T][c] = ldb8(Wr + (size_t)(16*T + l15) * HH + 32*c + lg*8);
  f16x8 bWo[2][2];
  #pragma unroll
  for (int T = 0; T < 2; ++T)
    #pragma unroll
    for (int c = 0; c < 2; ++c)
      bWo[T][c] = ldb8(Wout + (size_t)(16*T + l15) * HH + 32*c + lg*8);
  f16x8 bWt[4];
  #pragma unroll
  for (int T = 0; T < 4; ++T)
    bWt[T] = ldb8(wotT + (size_t)(16*T + l15) * NOB + lg*8);

  // ---- phase 1: x A-frags + row stats ----
  const float4* __restrict__ xr = (const float4*)(x + (size_t)(rbase + l15) * HH);
  float4 xa0 = xr[lg*2],     xa1 = xr[lg*2 + 1];
  float4 xb0 = xr[8 + lg*2], xb1 = xr[8 + lg*2 + 1];
  f16x8 ax0, ax1;
  {
    f16x8 r;
    r[0]=(_Float16)xa0.x; r[1]=(_Float16)xa0.y; r[2]=(_Float16)xa0.z; r[3]=(_Float16)xa0.w;
    r[4]=(_Float16)xa1.x; r[5]=(_Float16)xa1.y; r[6]=(_Float16)xa1.z; r[7]=(_Float16)xa1.w;
    ax0 = r;
    r[0]=(_Float16)xb0.x; r[1]=(_Float16)xb0.y; r[2]=(_Float16)xb0.z; r[3]=(_Float16)xb0.w;
    r[4]=(_Float16)xb1.x; r[5]=(_Float16)xb1.y; r[6]=(_Float16)xb1.z; r[7]=(_Float16)xb1.w;
    ax1 = r;
  }
  float ssx = SUMSQ4(xa0)+SUMSQ4(xa1)+SUMSQ4(xb0)+SUMSQ4(xb1);
  float sx  = SUM4(xa0)+SUM4(xa1)+SUM4(xb0)+SUM4(xb1);
  ssx += __shfl_xor(ssx, 16); ssx += __shfl_xor(ssx, 32);
  sx  += __shfl_xor(sx, 16);  sx  += __shfl_xor(sx, 32);
  float inv_x = 1.f / (sqrtf(ssx) + EPSV);   // row l15

  // ---- GEMM1: acc[T] = x @ Wr^T tile ----
  f32x4v acc[4];
  #pragma unroll
  for (int T = 0; T < 4; ++T) {
    f32x4v c = {0.f, 0.f, 0.f, 0.f};
    c = MFMA16(ax0, bWr[T][0], c);
    c = MFMA16(ax1, bWr[T][1], c);
    acc[T] = c;
  }

  // ---- phase 3: s0 = relu(inv_x*acc + drive); D rows r=4lg+reg, col h=16T+l15 ----
  float invxr[4], sxr[4];
  int dirr[4], obr[4];
  #pragma unroll
  for (int reg = 0; reg < 4; ++reg) {
    invxr[reg] = __shfl(inv_x, 4*lg + reg);
    sxr[reg]   = __shfl(sx,    4*lg + reg);
    dirr[reg]  = dirs[rbase + 4*lg + reg];
    obr[reg]   = obs [rbase + 4*lg + reg];
  }
  float s0v[4][4];    // [T][reg]
  float ssg[4] = {0.f,0.f,0.f,0.f}, sgv[4] = {0.f,0.f,0.f,0.f};
  #pragma unroll
  for (int T = 0; T < 4; ++T)
    #pragma unroll
    for (int reg = 0; reg < 4; ++reg) {
      float drive = winT[dirr[reg] * HH + 16*T + l15];
      float v = fmaxf(fmaf(invxr[reg], acc[T][reg], drive), 0.f);
      s0v[T][reg] = v;
      ssg[reg] += v * v; sgv[reg] += v;
    }
  #pragma unroll
  for (int reg = 0; reg < 4; ++reg) {
    #pragma unroll
    for (int m = 1; m < 16; m <<= 1) {
      ssg[reg] += __shfl_xor(ssg[reg], m);
      sgv[reg] += __shfl_xor(sgv[reg], m);
    }
  }
  float invg[4];
  #pragma unroll
  for (int reg = 0; reg < 4; ++reg) invg[reg] = 1.f / (sqrtf(ssg[reg]) + EPSV);
  if (l15 == 0) {
    #pragma unroll
    for (int reg = 0; reg < 4; ++reg) scl0[rbase + 4*lg + reg] = invg[reg];
  }
  float g0 = 0.f;
  if (l15 == 0) {
    #pragma unroll
    for (int reg = 0; reg < 4; ++reg)
      g0 += invxr[reg] * sxr[reg] - invg[reg] * sgv[reg];
  }

  // s0 -> LDS tile ; coalesced buf0 write
  #pragma unroll
  for (int T = 0; T < 4; ++T)
    #pragma unroll
    for (int reg = 0; reg < 4; ++reg)
      s0l[(4*lg + reg) * 68 + 16*T + l15] = s0v[T][reg];
  {
    int rr = l >> 2, cc = (l & 3) * 16;
    const float4* srcl = (const float4*)(s0l + rr * 68 + cc);
    float4* dst = (float4*)(buf0 + (size_t)(rbase + rr) * HH + cc);
    dst[0] = srcl[0]; dst[1] = srcl[1]; dst[2] = srcl[2]; dst[3] = srcl[3];
  }

  // ---- GEMM2: logits = s0 @ WoutT ----
  f16x8 as0, as1;
  {
    const float* pr = s0l + l15 * 68 + lg * 8;
    as0 = ldb8(pr);
    as1 = ldb8(pr + 32);
  }
  f32x4v lac[2];
  #pragma unroll
  for (int T = 0; T < 2; ++T) {
    f32x4v c = {0.f, 0.f, 0.f, 0.f};
    c = MFMA16(as0, bWo[T][0], c);
    c = MFMA16(as1, bWo[T][1], c);
    lac[T] = c;
  }

  // ---- phase 5: softmax + jacobian per row ----
  float jp0[4], jp1[4];
  #pragma unroll
  for (int reg = 0; reg < 4; ++reg) {
    float z0 = lac[0][reg], z1 = lac[1][reg];
    float m = fmaxf(z0, z1);
    #pragma unroll
    for (int mm = 1; mm < 16; mm <<= 1) m = fmaxf(m, __shfl_xor(m, mm));
    float e0 = __expf(invg[reg] * (z0 - m));
    float e1 = __expf(invg[reg] * (z1 - m));
    float se = e0 + e1;
    #pragma unroll
    for (int mm = 1; mm < 16; mm <<= 1) se += __shfl_xor(se, mm);
    float rse = 1.f / se;
    float f0 = e0 * rse, f1 = e1 * rse;
    int ob = obr[reg];
    float on0 = (l15 == ob) ? 1.f : 0.f;
    float on1 = (16 + l15 == ob) ? 1.f : 0.f;
    float fob = on0 * f0 + on1 * f1;
    float sf2 = f0 * f0 + f1 * f1;
    #pragma unroll
    for (int mm = 1; mm < 16; mm <<= 1) {
      fob += __shfl_xor(fob, mm);
      sf2 += __shfl_xor(sf2, mm);
    }
    float fe = fob - sf2;
    jp0[reg] = f0 * (on0 - f0 - fe);
    jp1[reg] = f1 * (on1 - f1 - fe);
  }

  #pragma unroll
  for (int reg = 0; reg < 4; ++reg) {
    jpl[(4*lg + reg) * 36 + l15]      = jp0[reg];
    jpl[(4*lg + reg) * 36 + 16 + l15] = jp1[reg];
  }
  f16x8 ajp;
  {
    const float* pr = jpl + l15 * 36 + lg * 8;
    ajp = ldb8(pr);
  }

  // ---- GEMM3: pv = jp @ Wout ----
  f32x4v pv[4];
  #pragma unroll
  for (int T = 0; T < 4; ++T) {
    f32x4v c = {0.f, 0.f, 0.f, 0.f};
    pv[T] = MFMA16(ajp, bWt[T], c);
  }

  // ---- phase 8: s1 = sv + LR*(s0 - sv + pv); normalize IN PLACE; gates ----
  float ssu[4] = {0.f,0.f,0.f,0.f}, suv[4] = {0.f,0.f,0.f,0.f};
  #pragma unroll
  for (int T = 0; T < 4; ++T)
    #pragma unroll
    for (int reg = 0; reg < 4; ++reg) {
      float s0_ = s0v[T][reg];
      float sv = invg[reg] * s0_;
      float u = fmaf(LR_IT, s0_ - sv + pv[T][reg], sv);
      s0v[T][reg] = u;            // raw s1
      ssu[reg] += u * u; suv[reg] += u;
    }
  #pragma unroll
  for (int reg = 0; reg < 4; ++reg) {
    #pragma unroll
    for (int m = 1; m < 16; m <<= 1) {
      ssu[reg] += __shfl_xor(ssu[reg], m);
      suv[reg] += __shfl_xor(suv[reg], m);
    }
  }
  float invu[4];
  #pragma unroll
  for (int reg = 0; reg < 4; ++reg) invu[reg] = 1.f / (sqrtf(ssu[reg]) + EPSV);
  // buf1 holds NORMALIZED s1 -> effective downstream scale is 1.0
  if (l15 == 0) {
    #pragma unroll
    for (int reg = 0; reg < 4; ++reg) scl1[rbase + 4*lg + reg] = 1.0f;
  }
  float g1 = 0.f;
  if (l15 == 0) {
    #pragma unroll
    for (int reg = 0; reg < 4; ++reg)
      g1 += invg[reg] * sgv[reg] - invu[reg] * suv[reg];
  }
  #pragma unroll
  for (int T = 0; T < 4; ++T)
    #pragma unroll
    for (int reg = 0; reg < 4; ++reg)
      s0v[T][reg] *= invu[reg];   // normalized s1

  // normalized s1 -> LDS tile -> coalesced buf1 (= out s-slice) write
  #pragma unroll
  for (int T = 0; T < 4; ++T)
    #pragma unroll
    for (int reg = 0; reg < 4; ++reg)
      s0l[(4*lg + reg) * 68 + 16*T + l15] = s0v[T][reg];
  {
    int rr = l >> 2, cc = (l & 3) * 16;
    const float4* srcl = (const float4*)(s0l + rr * 68 + cc);
    float4* dst = (float4*)(buf1 + (size_t)(rbase + rr) * HH + cc);
    dst[0] = srcl[0]; dst[1] = srcl[1]; dst[2] = srcl[2]; dst[3] = srcl[3];
  }

  // ---- speculative final: preds = softmax(s1n @ WoutT) -> out[:B*32] ----
  {
    const float* pr = s0l + l15 * 68 + lg * 8;
    f16x8 a0 = ldb8(pr);
    f16x8 a1 = ldb8(pr + 32);
    f32x4v pl0 = {0.f,0.f,0.f,0.f}, pl1 = {0.f,0.f,0.f,0.f};
    pl0 = MFMA16(a0, bWo[0][0], pl0); pl0 = MFMA16(a1, bWo[0][1], pl0);
    pl1 = MFMA16(a0, bWo[1][0], pl1); pl1 = MFMA16(a1, bWo[1][1], pl1);
    #pragma unroll
    for (int reg = 0; reg < 4; ++reg) {
      float z0 = pl0[reg], z1 = pl1[reg];
      float m = fmaxf(z0, z1);
      #pragma unroll
      for (int mm = 1; mm < 16; mm <<= 1) m = fmaxf(m, __shfl_xor(m, mm));
      float e0 = __expf(z0 - m), e1 = __expf(z1 - m);
      float se = e0 + e1;
      #pragma unroll
      for (int mm = 1; mm < 16; mm <<= 1) se += __shfl_xor(se, mm);
      float rse = 1.f / se;
      jpl[(4*lg + reg) * 36 + l15]      = e0 * rse;
      jpl[(4*lg + reg) * 36 + 16 + l15] = e1 * rse;
    }
    int rr = l >> 2, cc = (l & 3) * 8;
    const float4* srcl = (const float4*)(jpl + rr * 36 + cc);
    float4* dst = (float4*)(out + (size_t)(rbase + rr) * NOB + cc);
    dst[0] = srcl[0]; dst[1] = srcl[1];
  }

  // ---- gates: wave totals -> block totals ----
  g0 += __shfl_xor(g0, 16); g0 += __shfl_xor(g0, 32);
  g1 += __shfl_xor(g1, 16); g1 += __shfl_xor(g1, 32);
  if (l == 0) { red0[w] = g0; red1[w] = g1; }
  __syncthreads();
  if (t == 0) {
    partials0[blockIdx.x] = red0[0] + red0[1] + red0[2] + red0[3];
    partials1[blockIdx.x] = red1[0] + red1[1] + red1[2] + red1[3];
  }
}

// ---- resolve: decide act0/act1; expected path is a no-op (fused wrote output) ----
__global__ __launch_bounds__(TPB, 2) void resolve_kernel(
    float* __restrict__ buf0, float* __restrict__ buf1,
    float* __restrict__ scl0, float* __restrict__ scl1,
    const float* __restrict__ Wr, const float* __restrict__ Wout,
    const float* __restrict__ Win,
    const int* __restrict__ dirs, const int* __restrict__ obs,
    const float* __restrict__ partials0, float* __restrict__ partials,
    int* __restrict__ actArr, float* __restrict__ out)
{
  __shared__ float wrl[HH * WRS];
  __shared__ float wot[HH * WOS];
  __shared__ float wint[NDIRS * WRS];
  __shared__ float red[4];
  int t = threadIdx.x;

  float t0v = gate_reduce_nbf(partials0, red, t);
  int act0 = (fabsf(t0v * INV_BH) > TOLV) ? 1 : 0;
  float t1v = gate_reduce_nbf(partials, red, t);
  int act1 = (fabsf(t1v * INV_BH) > TOLV) ? 1 : 0;
  if (blockIdx.x == 0 && t == 0) actArr[1] = act0 && act1;

  int r = blockIdx.x * TPB + t;

  if (!act0) {
    // iteration 0 inactive: final = s0 (overwrite speculative s1 output)
    if (t < 4) partials[blockIdx.x * 4 + t] = partials0[blockIdx.x * 4 + t];
    stage_wot(Wout, wot, t, TPB);
    __syncthreads();
    final_write(r, scl0[r], buf0, out, wot);
    return;
  }
  if (!act1) return;   // EXPECTED PATH: fused already wrote preds + normalized s1

  // both active: run iteration 1 fully. S=buf1 (normalized, scl1==1), P=buf0, W=buf0/scl0.
  stage_wr(Wr, wrl, t, TPB);
  stage_wot(Wout, wot, t, TPB);
  stage_wint(Win, wint, t, TPB);
  __syncthreads();

  float a_s = scl1[r];
  float a_p = scl0[r];
  int ob = obs[r];
  int dir = dirs[r];
  const float4* __restrict__ sr4 = (const float4*)(buf1 + (size_t)r * HH);

  float zz[NOB];
  #pragma unroll
  for (int o = 0; o < NOB; ++o) zz[o] = 0.f;
  float sS = 0.f;
  #pragma unroll 1
  for (int h0 = 0; h0 < 16; ++h0) {
    float4 s4 = sr4[h0];
    sS += SUM4(s4);
    const float* t0 = &wot[(h0 * 4 + 0) * WOS];
    const float* t1 = &wot[(h0 * 4 + 1) * WOS];
    const float* t2 = &wot[(h0 * 4 + 2) * WOS];
    const float* t3 = &wot[(h0 * 4 + 3) * WOS];
    #pragma unroll
    for (int o = 0; o < NOB; ++o)
      zz[o] += s4.x * t0[o] + s4.y * t1[o] + s4.z * t2[o] + s4.w * t3[o];
  }
  SOFTJP(zz, a_s, ob)
  __syncthreads();   // live-range firewall

  const float4* __restrict__ pr4 = (const float4*)(buf0 + (size_t)r * HH);
  LOADP(pr4);
  float4* wo4 = (float4*)(buf0 + (size_t)r * HH);
  float ssu = 0.f, su = 0.f;
#define STEP_C_ONE(JJ, COMP) { \
    const float* wr_ = &wrl[(h0 * 4 + JJ) * WRS]; \
    float g_ = fmaxf(fmaf(a_p, DOT64P(wr_), d4.COMP), 0.f); \
    const float* wt_ = &wot[(h0 * 4 + JJ) * WOS]; \
    float w_ = 0.f; \
    _Pragma("unroll") \
    for (int o = 0; o < NOB; ++o) w_ += zz[o] * wt_[o]; \
    float sv_ = a_s * s4.COMP; \
    float uu_ = fmaf(LR_IT, g_ - sv_ + w_, sv_); \
    u.COMP = uu_; ssu += uu_ * uu_; su += uu_; }
  #pragma unroll 1
  for (int h0 = 0; h0 < 16; ++h0) {
    float4 s4 = sr4[h0];
    float4 d4 = *(const float4*)&wint[dir * WRS + h0 * 4];
    float4 u;
    STEP_C_ONE(0, x) STEP_C_ONE(1, y) STEP_C_ONE(2, z) STEP_C_ONE(3, w)
    wo4[h0] = u;
  }
  float inv_u = 1.f / (sqrtf(ssu) + EPSV);
  scl0[r] = inv_u;

  float tot2 = block_reduce_all(a_s * sS - inv_u * su, red, t);
  if (t == 0) partials[blockIdx.x] = tot2;
  if (t == 1) partials[blockIdx.x + NBLK] = 0.f;
  if (t == 2) partials[blockIdx.x + 2 * NBLK] = 0.f;
  if (t == 3) partials[blockIdx.x + 3 * NBLK] = 0.f;
}

// ---- generic step k>=2: gate + (active | first-inactive final | no-op) ----
__global__ __launch_bounds__(TPB, 2) void step_kernel(
    float* __restrict__ buf0, float* __restrict__ buf1,
    float* __restrict__ scl0, float* __restrict__ scl1,
    const float* __restrict__ Wr, const float* __restrict__ Wout,
    const float* __restrict__ Win,
    const int* __restrict__ dirs, const int* __restrict__ obs,
    float* __restrict__ partials, int* __restrict__ actArr,
    float* __restrict__ out, int k)
{
  __shared__ float red[4];
  __shared__ float wrl[HH * WRS];
  __shared__ float wot[HH * WOS];
  __shared__ float wint[NDIRS * WRS];
  int t = threadIdx.x;

  float tot = gate_reduce_nbf(partials, red, t);
  int active = (fabsf(tot * INV_BH) > TOLV) ? 1 : 0;
  if (blockIdx.x == 0 && t == 0) actArr[k] = active;

  int si = k & 1;
  int r = blockIdx.x * TPB + t;

  if (!active) {
    int first_inactive = actArr[k - 1];
    if (!first_inactive) return;
    stage_wot(Wout, wot, t, TPB);
    __syncthreads();
    const float* S   = si ? buf1 : buf0;
    const float* scl = si ? scl1 : scl0;
    final_write(r, scl[r], S, out, wot);
    return;
  }

  const float* S    = si ? buf1 : buf0;
  const float* sclS = si ? scl1 : scl0;
  float* W          = si ? buf0 : buf1;
  float* sclW       = si ? scl0 : scl1;

  stage_wr(Wr, wrl, t, TPB);
  stage_wot(Wout, wot, t, TPB);
  stage_wint(Win, wint, t, TPB);
  __syncthreads();

  float a_s = sclS[r];
  float a_p = sclW[r];
  int ob = obs[r];
  int dir = dirs[r];
  const float4* __restrict__ sr4 = (const float4*)(S + (size_t)r * HH);

  float zz[NOB];
  #pragma unroll
  for (int o = 0; o < NOB; ++o) zz[o] = 0.f;
  float sS = 0.f;
  #pragma unroll 1
  for (int h0 = 0; h0 < 16; ++h0) {
    float4 s4 = sr4[h0];
    sS += SUM4(s4);
    const float* t0 = &wot[(h0 * 4 + 0) * WOS];
    const float* t1 = &wot[(h0 * 4 + 1) * WOS];
    const float* t2 = &wot[(h0 * 4 + 2) * WOS];
    const float* t3 = &wot[(h0 * 4 + 3) * WOS];
    #pragma unroll
    for (int o = 0; o < NOB; ++o)
      zz[o] += s4.x * t0[o] + s4.y * t1[o] + s4.z * t2[o] + s4.w * t3[o];
  }
  SOFTJP(zz, a_s, ob)
  __syncthreads();

  const float4* __restrict__ pr4 = (const float4*)(W + (size_t)r * HH);
  LOADP(pr4);
  float4* wo4 = (float4*)(W + (size_t)r * HH);
  float ssu = 0.f, su = 0.f;
  #pragma unroll 1
  for (int h0 = 0; h0 < 16; ++h0) {
    float4 s4 = sr4[h0];
    float4 d4 = *(const float4*)&wint[dir * WRS + h0 * 4];
    float4 u;
    STEP_C_ONE(0, x) STEP_C_ONE(1, y) STEP_C_ONE(2, z) STEP_C_ONE(3, w)
    wo4[h0] = u;
  }
  float inv_u = 1.f / (sqrtf(ssu) + EPSV);
  sclW[r] = inv_u;

  float tot2 = block_reduce_all(a_s * sS - inv_u * su, red, t);
  if (t == 0) partials[blockIdx.x] = tot2;
  if (t == 1) partials[blockIdx.x + NBLK] = 0.f;
  if (t == 2) partials[blockIdx.x + 2 * NBLK] = 0.f;
  if (t == 3) partials[blockIdx.x + 3 * NBLK] = 0.f;
}

// ---- tail: only fires when all 10 iterations were active ----
__global__ __launch_bounds__(TPB, 2) void final_kernel(
    const float* __restrict__ buf0, float* __restrict__ out,
    const float* __restrict__ scl0,
    const float* __restrict__ Wout, const int* __restrict__ actArr)
{
  if (actArr[9] == 0) return;
  __shared__ float wot[HH * WOS];
  int t = threadIdx.x;
  stage_wot(Wout, wot, t, TPB);
  __syncthreads();
  int r = blockIdx.x * TPB + t;
  final_write(r, scl0[r], buf0, out, wot);
}

extern "C" void kernel_launch(void* const* d_in, const int* in_sizes, int n_in,
                              void* d_out, int out_size, void* d_ws, size_t ws_size,
                              hipStream_t stream) {
  const int* dirs = (const int*)d_in[0];
  const int* obs = (const int*)d_in[1];
  const float* x = (const float*)d_in[2];
  const float* Wr = (const float*)d_in[3];
  const float* Win = (const float*)d_in[4];
  const float* Wout = (const float*)d_in[5];
  float* out = (float*)d_out;
  float* ws = (float*)d_ws;

  float* buf0 = ws;                              // B*H raw state s0 (then s2,..)
  float* scl0 = ws + (size_t)BB * HH;            // B
  float* scl1 = scl0 + BB;                       // B
  float* partials = scl1 + BB;                   // NBF (gate for "current" iteration)
  float* partials0 = partials + NBF;             // NBF (gate0)
  int* actArr = (int*)(partials0 + NBF);         // 16 ints
  float* wotT = (float*)(actArr + 16);           // 64*32
  float* winT = wotT + NOB * HH;                 // 8*64
  float* buf1 = out + (size_t)BB * NOB;          // s-slice of d_out: s1 (normalized)

  prep_kernel<<<1, TPB, 0, stream>>>(Wout, Win, wotT, winT);
  fused_kernel<<<NBF, TPB, 0, stream>>>(x, dirs, obs, Wr, Wout, wotT, winT,
                                        buf0, buf1, scl0, scl1, partials0, partials, out);
  resolve_kernel<<<NBLK, TPB, 0, stream>>>(buf0, buf1, scl0, scl1, Wr, Wout, Win,
                                           dirs, obs, partials0, partials, actArr, out);
  for (int k = 2; k < 10; ++k)
    step_kernel<<<NBLK, TPB, 0, stream>>>(buf0, buf1, scl0, scl1,
                                          Wr, Wout, Win, dirs, obs, partials, actArr, out, k);
  final_kernel<<<NBLK, TPB, 0, stream>>>(buf0, out, scl0, Wout, actArr);
}